// Round 6
// baseline (127.287 us; speedup 1.0000x reference)
//
#include <hip/hip_runtime.h>

// KPN per-pixel 5x5 predicted convolution, channels-last fp32.
// out[b,h,w,c] = sum_{i,j} feat[b,h+i-2,w+j-2,c] * kernel[b,h,w,i*5+j] + bias[c]
//
// Round 13: feat LDS staging DELETED; feat read direct global->VGPR.
//  - R12 profile (first time kernel visible): 43.5us, 1.53 TB/s (19% HBM),
//    VALUBusy 15%, Occupancy 18.9%, conflicts 0. Everything idle =>
//    LATENCY/OCCUPANCY-bound, not HBM-bound (refutes R9-R11 theory).
//    Cause: monolithic 81KB vmcnt(0) drain + only 2 blocks/CU.
//  - Fix: feat's LDS round-trip only provided 5-tap horizontal sharing,
//    which L1 (32KB/CU) provides for coalesced row reads. Read feat
//    directly (60 clamped global_load_dwordx4/thread, 1-row-ahead
//    software prefetch, statically-named double buffers). Keep only the
//    25.6KB weight stage in LDS (8x cg-broadcast, 25 async issues).
//  - Boundary: zero OOB weight TAPS in LDS (edge blocks only); feat
//    addresses clamped => products exactly 0, bitwise-identical math.
//  - LDS 80896 -> 25600 B; __launch_bounds__(256,4) caps VGPR at 128 =>
//    4 blocks/CU, 16 waves/CU (entire 1024-block grid resident).
//  - Predict: Occupancy ~45%, VALUBusy ~35%, kernel 43.5 -> ~22us,
//    dur_us ~85. Failure mode to watch: VGPR spill to scratch.

#define BB 4
#define HH 256
#define WW 256
#define CC 32
#define KK 5
#define VH 8                    // output rows per block
#define TW 32                   // tile width (pixels)
#define TPB 256                 // 4 waves
#define TROWS (VH + KK - 1)     // 12 feat rows touched
#define SK_F4 (VH * TW * KK * KK / 4)    // 1600 float4 = 25.6 KB
#define NQK (SK_F4 / 64)        // 25 weight async issues

typedef __attribute__((address_space(1))) const void gvoid_t;
typedef __attribute__((address_space(3))) void svoid_t;
typedef float vfloat4 __attribute__((ext_vector_type(4)));

__global__ __launch_bounds__(TPB, 4) void kpn_conv_kernel(
    const float* __restrict__ feat,
    const float* __restrict__ kern,
    const float* __restrict__ bias,
    float* __restrict__ out)
{
    __shared__ float4 sb[SK_F4];   // 25,600 B: weights only

    const int t    = threadIdx.x;
    const int lane = t & 63;
    const int wave = t >> 6;

    const int bw = blockIdx.x & 7;            // W/TW = 8
    const int bh = (blockIdx.x >> 3) & 31;    // H/VH = 32
    const int b  = blockIdx.x >> 8;           // B = 4
    const int h0 = bh * VH;
    const int w0 = bw * TW;

    const float* fb = feat + (((size_t)b) << 16) * CC;
    const float* kb = kern + (size_t)((b * HH + h0) * WW + w0) * (KK * KK);

    // ---- Async weight staging: 25 wave-issues, 25.6 KB. ----
    for (int q = wave; q < NQK; q += TPB / 64) {
        int e   = (q << 6) + lane;               // f4 idx 0..1599 exact
        int oh  = e / 200;                       // 200 f4 per output row
        int off = (e - oh * 200) << 2;           // float offset
        const float* gp = kb + (size_t)oh * (WW * KK * KK) + off;
        __builtin_amdgcn_global_load_lds((gvoid_t*)gp,
                                         (svoid_t*)(sb + (q << 6)),
                                         16, 0, 0);
    }
    __syncthreads();   // drains vmcnt (25.6 KB only)

    float* skw_w = (float*)sb;
    const bool wlo = (w0 == 0), whi = (w0 == WW - TW);
    const bool top = (h0 == 0), bot = (h0 == HH - VH);

    // ---- Edge blocks: zero OOB weight taps (block-uniform branch). ----
    if (wlo || whi || top || bot) {
        if (wlo) {   // (px=0,j=0),(px=0,j=1),(px=1,j=0) for all oh,i
            for (int s = t; s < VH * 15; s += TPB) {
                int oh = s / 15, rr = s % 15, i = rr / 3, c = rr % 3;
                int px = (c == 2) ? 1 : 0, j = (c == 2) ? 0 : c;
                skw_w[(oh * TW + px) * 25 + i * 5 + j] = 0.f;
            }
        }
        if (whi) {   // (31,3),(31,4),(30,4)
            for (int s = t; s < VH * 15; s += TPB) {
                int oh = s / 15, rr = s % 15, i = rr / 3, c = rr % 3;
                int px = (c == 2) ? 30 : 31, j = (c == 2) ? 4 : (3 + c);
                skw_w[(oh * TW + px) * 25 + i * 5 + j] = 0.f;
            }
        }
        if (top) {   // rows h0+oh+i-2 < 0: (oh,i) = (0,0),(0,1),(1,0)
            for (int s = t; s < TW * KK; s += TPB) {
                int px = s / KK, j = s % KK;
                skw_w[(0 * TW + px) * 25 + 0 * 5 + j] = 0.f;
                skw_w[(0 * TW + px) * 25 + 1 * 5 + j] = 0.f;
                skw_w[(1 * TW + px) * 25 + 0 * 5 + j] = 0.f;
            }
        }
        if (bot) {   // rows > 255: (oh,i) = (6,4),(7,3),(7,4)
            for (int s = t; s < TW * KK; s += TPB) {
                int px = s / KK, j = s % KK;
                skw_w[(6 * TW + px) * 25 + 4 * 5 + j] = 0.f;
                skw_w[(7 * TW + px) * 25 + 3 * 5 + j] = 0.f;
                skw_w[(7 * TW + px) * 25 + 4 * 5 + j] = 0.f;
            }
        }
        __syncthreads();
    }

    // ---- Compute: feat direct from global, weights from LDS. ----
    const int cg = (t & 7) << 2;   // channel group (floats)
    const int wL = t >> 3;         // 0..31
    const float* skw = (const float*)sb;

    // Clamped per-j column float-offsets (OOB contributions killed by
    // zeroed weights, so clamped reads are exact).
    int wofs[KK];
    #pragma unroll
    for (int j = 0; j < KK; ++j)
        wofs[j] = min(max(w0 + wL + j - (KK / 2), 0), WW - 1) * CC + cg;

    const float4 bz = *(const float4*)(bias + cg);
    float4 acc[VH];
    #pragma unroll
    for (int oh = 0; oh < VH; ++oh) acc[oh] = bz;

#define LOADROW(F, r) {                                                       \
        int hc = min(max(h0 + (r) - (KK / 2), 0), HH - 1);                    \
        const float* rp = fb + (size_t)hc * (WW * CC);                        \
        _Pragma("unroll")                                                     \
        for (int j = 0; j < KK; ++j)                                          \
            F[j] = *(const float4*)(rp + wofs[j]);                            \
    }

#define FMAROW(F, r) {                                                        \
        _Pragma("unroll")                                                     \
        for (int oh = 0; oh < VH; ++oh) {                                     \
            const int i = (r) - oh;                                           \
            if (i >= 0 && i < KK) {                                           \
                const float* wp = skw + (oh * TW + wL) * (KK * KK) + i * KK;  \
                const float wg0 = wp[0], wg1 = wp[1], wg2 = wp[2],            \
                            wg3 = wp[3], wg4 = wp[4];                         \
                acc[oh].x += F[0].x*wg0 + F[1].x*wg1 + F[2].x*wg2 + F[3].x*wg3 + F[4].x*wg4; \
                acc[oh].y += F[0].y*wg0 + F[1].y*wg1 + F[2].y*wg2 + F[3].y*wg3 + F[4].y*wg4; \
                acc[oh].z += F[0].z*wg0 + F[1].z*wg1 + F[2].z*wg2 + F[3].z*wg3 + F[4].z*wg4; \
                acc[oh].w += F[0].w*wg0 + F[1].w*wg1 + F[2].w*wg2 + F[3].w*wg3 + F[4].w*wg4; \
            }                                                                 \
        }                                                                     \
    }

    // 1-row-ahead software prefetch, statically-named double buffers.
    float4 fA[KK], fB[KK];
    LOADROW(fA, 0)
    LOADROW(fB, 1)  FMAROW(fA, 0)
    LOADROW(fA, 2)  FMAROW(fB, 1)
    LOADROW(fB, 3)  FMAROW(fA, 2)
    LOADROW(fA, 4)  FMAROW(fB, 3)
    LOADROW(fB, 5)  FMAROW(fA, 4)
    LOADROW(fA, 6)  FMAROW(fB, 5)
    LOADROW(fB, 7)  FMAROW(fA, 6)
    LOADROW(fA, 8)  FMAROW(fB, 7)
    LOADROW(fB, 9)  FMAROW(fA, 8)
    LOADROW(fA, 10) FMAROW(fB, 9)
    LOADROW(fB, 11) FMAROW(fA, 10)
                    FMAROW(fB, 11)

    // ---- Coalesced nontemporal stores: 8 rows x 1 KiB per wave. ----
    #pragma unroll
    for (int oh = 0; oh < VH; ++oh) {
        const size_t pix = (size_t)(b * HH + h0 + oh) * WW + (w0 + wL);
        vfloat4 v = { acc[oh].x, acc[oh].y, acc[oh].z, acc[oh].w };
        __builtin_nontemporal_store(v, (vfloat4*)(out + pix * CC + cg));
    }
}

extern "C" void kernel_launch(void* const* d_in, const int* in_sizes, int n_in,
                              void* d_out, int out_size, void* d_ws, size_t ws_size,
                              hipStream_t stream) {
    const float* feat = (const float*)d_in[0];
    const float* kern = (const float*)d_in[1];
    const float* bias = (const float*)d_in[2];
    float* out = (float*)d_out;

    dim3 grid(BB * (HH / VH) * (WW / TW));  // 1024 blocks
    dim3 block(TPB);
    kpn_conv_kernel<<<grid, block, 0, stream>>>(feat, kern, bias, out);
}

// Round 7
// 109.215 us; speedup vs baseline: 1.1655x; 1.1655x over previous
//
#include <hip/hip_runtime.h>

// KPN per-pixel 5x5 predicted convolution, channels-last fp32.
// out[b,h,w,c] = sum_{i,j} feat[b,h+i-2,w+j-2,c] * kernel[b,h,w,i*5+j] + bias[c]
//
// Round 14 = Round 13 (direct-feat) with __launch_bounds__(256,2).
//  - R13 post-mortem: (256,4) made the backend squeeze to the 64-VGPR
//    occupancy step (natural demand ~95) => scratch spills: WRITE_SIZE
//    73.7 MB vs 33.8 ideal (+40 MB scratch writeback ~ 160 B/thread =
//    exactly the fA/fB footprint), kernel 49.5us. Occupancy DID rise
//    (18.9 -> 28.8%) and reads were clean (FETCH 59.1 ~= feat+kern
//    ideal) => the direct-feat structure is right, the regalloc wasn't.
//  - Fix: launch_bounds(256,2) lifts the squeeze; ~95-110 VGPR natural,
//    no spill. <=128 VGPR still hardware-allows 4 waves/EU, LDS 25.6 KB
//    allows 6 blocks/CU => whole 1024-block grid resident (4 blocks/CU).
//  - Predict: VGPR ~96-112, WRITE back to ~33.8 MB, occupancy ~45-50%,
//    kernel ~28-33us, dur ~95-100. Watch: VGPR>128 => 2 waves/EU.

#define BB 4
#define HH 256
#define WW 256
#define CC 32
#define KK 5
#define VH 8                    // output rows per block
#define TW 32                   // tile width (pixels)
#define TPB 256                 // 4 waves
#define TROWS (VH + KK - 1)     // 12 feat rows touched
#define SK_F4 (VH * TW * KK * KK / 4)    // 1600 float4 = 25.6 KB
#define NQK (SK_F4 / 64)        // 25 weight async issues

typedef __attribute__((address_space(1))) const void gvoid_t;
typedef __attribute__((address_space(3))) void svoid_t;
typedef float vfloat4 __attribute__((ext_vector_type(4)));

__global__ __launch_bounds__(TPB, 2) void kpn_conv_kernel(
    const float* __restrict__ feat,
    const float* __restrict__ kern,
    const float* __restrict__ bias,
    float* __restrict__ out)
{
    __shared__ float4 sb[SK_F4];   // 25,600 B: weights only

    const int t    = threadIdx.x;
    const int lane = t & 63;
    const int wave = t >> 6;

    const int bw = blockIdx.x & 7;            // W/TW = 8
    const int bh = (blockIdx.x >> 3) & 31;    // H/VH = 32
    const int b  = blockIdx.x >> 8;           // B = 4
    const int h0 = bh * VH;
    const int w0 = bw * TW;

    const float* fb = feat + (((size_t)b) << 16) * CC;
    const float* kb = kern + (size_t)((b * HH + h0) * WW + w0) * (KK * KK);

    // ---- Async weight staging: 25 wave-issues, 25.6 KB. ----
    for (int q = wave; q < NQK; q += TPB / 64) {
        int e   = (q << 6) + lane;               // f4 idx 0..1599 exact
        int oh  = e / 200;                       // 200 f4 per output row
        int off = (e - oh * 200) << 2;           // float offset
        const float* gp = kb + (size_t)oh * (WW * KK * KK) + off;
        __builtin_amdgcn_global_load_lds((gvoid_t*)gp,
                                         (svoid_t*)(sb + (q << 6)),
                                         16, 0, 0);
    }
    __syncthreads();   // drains vmcnt (25.6 KB only)

    float* skw_w = (float*)sb;
    const bool wlo = (w0 == 0), whi = (w0 == WW - TW);
    const bool top = (h0 == 0), bot = (h0 == HH - VH);

    // ---- Edge blocks: zero OOB weight taps (block-uniform branch). ----
    if (wlo || whi || top || bot) {
        if (wlo) {   // (px=0,j=0),(px=0,j=1),(px=1,j=0) for all oh,i
            for (int s = t; s < VH * 15; s += TPB) {
                int oh = s / 15, rr = s % 15, i = rr / 3, c = rr % 3;
                int px = (c == 2) ? 1 : 0, j = (c == 2) ? 0 : c;
                skw_w[(oh * TW + px) * 25 + i * 5 + j] = 0.f;
            }
        }
        if (whi) {   // (31,3),(31,4),(30,4)
            for (int s = t; s < VH * 15; s += TPB) {
                int oh = s / 15, rr = s % 15, i = rr / 3, c = rr % 3;
                int px = (c == 2) ? 30 : 31, j = (c == 2) ? 4 : (3 + c);
                skw_w[(oh * TW + px) * 25 + i * 5 + j] = 0.f;
            }
        }
        if (top) {   // rows h0+oh+i-2 < 0: (oh,i) = (0,0),(0,1),(1,0)
            for (int s = t; s < TW * KK; s += TPB) {
                int px = s / KK, j = s % KK;
                skw_w[(0 * TW + px) * 25 + 0 * 5 + j] = 0.f;
                skw_w[(0 * TW + px) * 25 + 1 * 5 + j] = 0.f;
                skw_w[(1 * TW + px) * 25 + 0 * 5 + j] = 0.f;
            }
        }
        if (bot) {   // rows > 255: (oh,i) = (6,4),(7,3),(7,4)
            for (int s = t; s < TW * KK; s += TPB) {
                int px = s / KK, j = s % KK;
                skw_w[(6 * TW + px) * 25 + 4 * 5 + j] = 0.f;
                skw_w[(7 * TW + px) * 25 + 3 * 5 + j] = 0.f;
                skw_w[(7 * TW + px) * 25 + 4 * 5 + j] = 0.f;
            }
        }
        __syncthreads();
    }

    // ---- Compute: feat direct from global, weights from LDS. ----
    const int cg = (t & 7) << 2;   // channel group (floats)
    const int wL = t >> 3;         // 0..31
    const float* skw = (const float*)sb;

    // Clamped per-j column float-offsets (OOB contributions killed by
    // zeroed weights, so clamped reads are exact).
    int wofs[KK];
    #pragma unroll
    for (int j = 0; j < KK; ++j)
        wofs[j] = min(max(w0 + wL + j - (KK / 2), 0), WW - 1) * CC + cg;

    const float4 bz = *(const float4*)(bias + cg);
    float4 acc[VH];
    #pragma unroll
    for (int oh = 0; oh < VH; ++oh) acc[oh] = bz;

#define LOADROW(F, r) {                                                       \
        int hc = min(max(h0 + (r) - (KK / 2), 0), HH - 1);                    \
        const float* rp = fb + (size_t)hc * (WW * CC);                        \
        _Pragma("unroll")                                                     \
        for (int j = 0; j < KK; ++j)                                          \
            F[j] = *(const float4*)(rp + wofs[j]);                            \
    }

#define FMAROW(F, r) {                                                        \
        _Pragma("unroll")                                                     \
        for (int oh = 0; oh < VH; ++oh) {                                     \
            const int i = (r) - oh;                                           \
            if (i >= 0 && i < KK) {                                           \
                const float* wp = skw + (oh * TW + wL) * (KK * KK) + i * KK;  \
                const float wg0 = wp[0], wg1 = wp[1], wg2 = wp[2],            \
                            wg3 = wp[3], wg4 = wp[4];                         \
                acc[oh].x += F[0].x*wg0 + F[1].x*wg1 + F[2].x*wg2 + F[3].x*wg3 + F[4].x*wg4; \
                acc[oh].y += F[0].y*wg0 + F[1].y*wg1 + F[2].y*wg2 + F[3].y*wg3 + F[4].y*wg4; \
                acc[oh].z += F[0].z*wg0 + F[1].z*wg1 + F[2].z*wg2 + F[3].z*wg3 + F[4].z*wg4; \
                acc[oh].w += F[0].w*wg0 + F[1].w*wg1 + F[2].w*wg2 + F[3].w*wg3 + F[4].w*wg4; \
            }                                                                 \
        }                                                                     \
    }

    // 1-row-ahead software prefetch, statically-named double buffers.
    float4 fA[KK], fB[KK];
    LOADROW(fA, 0)
    LOADROW(fB, 1)  FMAROW(fA, 0)
    LOADROW(fA, 2)  FMAROW(fB, 1)
    LOADROW(fB, 3)  FMAROW(fA, 2)
    LOADROW(fA, 4)  FMAROW(fB, 3)
    LOADROW(fB, 5)  FMAROW(fA, 4)
    LOADROW(fA, 6)  FMAROW(fB, 5)
    LOADROW(fB, 7)  FMAROW(fA, 6)
    LOADROW(fA, 8)  FMAROW(fB, 7)
    LOADROW(fB, 9)  FMAROW(fA, 8)
    LOADROW(fA, 10) FMAROW(fB, 9)
    LOADROW(fB, 11) FMAROW(fA, 10)
                    FMAROW(fB, 11)

    // ---- Coalesced nontemporal stores: 8 rows x 1 KiB per wave. ----
    #pragma unroll
    for (int oh = 0; oh < VH; ++oh) {
        const size_t pix = (size_t)(b * HH + h0 + oh) * WW + (w0 + wL);
        vfloat4 v = { acc[oh].x, acc[oh].y, acc[oh].z, acc[oh].w };
        __builtin_nontemporal_store(v, (vfloat4*)(out + pix * CC + cg));
    }
}

extern "C" void kernel_launch(void* const* d_in, const int* in_sizes, int n_in,
                              void* d_out, int out_size, void* d_ws, size_t ws_size,
                              hipStream_t stream) {
    const float* feat = (const float*)d_in[0];
    const float* kern = (const float*)d_in[1];
    const float* bias = (const float*)d_in[2];
    float* out = (float*)d_out;

    dim3 grid(BB * (HH / VH) * (WW / TW));  // 1024 blocks
    dim3 block(TPB);
    kpn_conv_kernel<<<grid, block, 0, stream>>>(feat, kern, bias, out);
}

// Round 8
// 106.383 us; speedup vs baseline: 1.1965x; 1.0266x over previous
//
#include <hip/hip_runtime.h>

// KPN per-pixel 5x5 predicted convolution, channels-last fp32.
// out[b,h,w,c] = sum_{i,j} feat[b,h+i-2,w+j-2,c] * kernel[b,h,w,i*5+j] + bias[c]
//
// Round 15 = Round 14 (direct-feat, weights-in-LDS) + deeper pipeline.
//  - R14 post-mortem: kernel fell below all fills (<42us; ~22us by
//    subtraction). Corrected model (/=4 SIMDs!): VALU ~3.5us/CU, HBM
//    ~14.6us/CU => ~7us of EXPOSED LATENCY, not BW/VALU. Each wave had
//    1-row-ahead prefetch: per SIMD ~4 waves x 200cyc FMA cover ~= 800cyc
//    vs ~900cyc HBM latency -> leaks a stall every row.
//  - Fix 1: 2-row-ahead triple buffer (fA/fB/fC): 10 outstanding loads,
//    ~400cyc own-wave cover -> 2x latency tolerance. VGPR ~112, still
//    4 waves/EU, no spill (keep launch_bounds(256,2), R13 lesson).
//  - Fix 2: prefetch rows 0,1 BEFORE the weight-stage barrier: their HBM
//    latency rides under the 25.6KB weight drain (VGPR dest, no LDS
//    hazard; barrier's vmcnt(0) drain covers them).
//  - Predict: WRITE ~34MB (tripwire: spill), kernel ~17-18.5us,
//    dur ~100-103. If >=104: declare latency-floor roofline.

#define BB 4
#define HH 256
#define WW 256
#define CC 32
#define KK 5
#define VH 8                    // output rows per block
#define TW 32                   // tile width (pixels)
#define TPB 256                 // 4 waves
#define SK_F4 (VH * TW * KK * KK / 4)    // 1600 float4 = 25.6 KB
#define NQK (SK_F4 / 64)        // 25 weight async issues

typedef __attribute__((address_space(1))) const void gvoid_t;
typedef __attribute__((address_space(3))) void svoid_t;
typedef float vfloat4 __attribute__((ext_vector_type(4)));

__global__ __launch_bounds__(TPB, 2) void kpn_conv_kernel(
    const float* __restrict__ feat,
    const float* __restrict__ kern,
    const float* __restrict__ bias,
    float* __restrict__ out)
{
    __shared__ float4 sb[SK_F4];   // 25,600 B: weights only

    const int t    = threadIdx.x;
    const int lane = t & 63;
    const int wave = t >> 6;

    const int bw = blockIdx.x & 7;            // W/TW = 8
    const int bh = (blockIdx.x >> 3) & 31;    // H/VH = 32
    const int b  = blockIdx.x >> 8;           // B = 4
    const int h0 = bh * VH;
    const int w0 = bw * TW;

    const float* fb = feat + (((size_t)b) << 16) * CC;
    const float* kb = kern + (size_t)((b * HH + h0) * WW + w0) * (KK * KK);

    // ---- Async weight staging: 25 wave-issues, 25.6 KB. ----
    for (int q = wave; q < NQK; q += TPB / 64) {
        int e   = (q << 6) + lane;               // f4 idx 0..1599 exact
        int oh  = e / 200;                       // 200 f4 per output row
        int off = (e - oh * 200) << 2;           // float offset
        const float* gp = kb + (size_t)oh * (WW * KK * KK) + off;
        __builtin_amdgcn_global_load_lds((gvoid_t*)gp,
                                         (svoid_t*)(sb + (q << 6)),
                                         16, 0, 0);
    }

    // ---- Thread mapping + clamped column offsets (needed for prefetch). ----
    const int cg = (t & 7) << 2;   // channel group (floats)
    const int wL = t >> 3;         // 0..31

    int wofs[KK];
    #pragma unroll
    for (int j = 0; j < KK; ++j)
        wofs[j] = min(max(w0 + wL + j - (KK / 2), 0), WW - 1) * CC + cg;

#define LOADROW(F, r) {                                                       \
        int hc = min(max(h0 + (r) - (KK / 2), 0), HH - 1);                    \
        const float* rp = fb + (size_t)hc * (WW * CC);                        \
        _Pragma("unroll")                                                     \
        for (int j = 0; j < KK; ++j)                                          \
            F[j] = *(const float4*)(rp + wofs[j]);                            \
    }

    // Prefetch rows 0,1 into VGPRs BEFORE the barrier: their HBM latency
    // overlaps the weight-stage drain (no LDS hazard; VGPR destination).
    float4 fA[KK], fB[KK], fC[KK];
    const float4 bz = *(const float4*)(bias + cg);
    LOADROW(fA, 0)
    LOADROW(fB, 1)

    __syncthreads();   // drains vmcnt (weight stage + prefetch all landed)

    float* skw_w = (float*)sb;
    const bool wlo = (w0 == 0), whi = (w0 == WW - TW);
    const bool top = (h0 == 0), bot = (h0 == HH - VH);

    // ---- Edge blocks: zero OOB weight taps (block-uniform branch). ----
    if (wlo || whi || top || bot) {
        if (wlo) {   // (px=0,j=0),(px=0,j=1),(px=1,j=0) for all oh,i
            for (int s = t; s < VH * 15; s += TPB) {
                int oh = s / 15, rr = s % 15, i = rr / 3, c = rr % 3;
                int px = (c == 2) ? 1 : 0, j = (c == 2) ? 0 : c;
                skw_w[(oh * TW + px) * 25 + i * 5 + j] = 0.f;
            }
        }
        if (whi) {   // (31,3),(31,4),(30,4)
            for (int s = t; s < VH * 15; s += TPB) {
                int oh = s / 15, rr = s % 15, i = rr / 3, c = rr % 3;
                int px = (c == 2) ? 30 : 31, j = (c == 2) ? 4 : (3 + c);
                skw_w[(oh * TW + px) * 25 + i * 5 + j] = 0.f;
            }
        }
        if (top) {   // rows h0+oh+i-2 < 0: (oh,i) = (0,0),(0,1),(1,0)
            for (int s = t; s < TW * KK; s += TPB) {
                int px = s / KK, j = s % KK;
                skw_w[(0 * TW + px) * 25 + 0 * 5 + j] = 0.f;
                skw_w[(0 * TW + px) * 25 + 1 * 5 + j] = 0.f;
                skw_w[(1 * TW + px) * 25 + 0 * 5 + j] = 0.f;
            }
        }
        if (bot) {   // rows > 255: (oh,i) = (6,4),(7,3),(7,4)
            for (int s = t; s < TW * KK; s += TPB) {
                int px = s / KK, j = s % KK;
                skw_w[(6 * TW + px) * 25 + 4 * 5 + j] = 0.f;
                skw_w[(7 * TW + px) * 25 + 3 * 5 + j] = 0.f;
                skw_w[(7 * TW + px) * 25 + 4 * 5 + j] = 0.f;
            }
        }
        __syncthreads();
    }

    // ---- Compute: feat direct from global, weights from LDS. ----
    const float* skw = (const float*)sb;

    float4 acc[VH];
    #pragma unroll
    for (int oh = 0; oh < VH; ++oh) acc[oh] = bz;

#define FMAROW(F, r) {                                                        \
        _Pragma("unroll")                                                     \
        for (int oh = 0; oh < VH; ++oh) {                                     \
            const int i = (r) - oh;                                           \
            if (i >= 0 && i < KK) {                                           \
                const float* wp = skw + (oh * TW + wL) * (KK * KK) + i * KK;  \
                const float wg0 = wp[0], wg1 = wp[1], wg2 = wp[2],            \
                            wg3 = wp[3], wg4 = wp[4];                         \
                acc[oh].x += F[0].x*wg0 + F[1].x*wg1 + F[2].x*wg2 + F[3].x*wg3 + F[4].x*wg4; \
                acc[oh].y += F[0].y*wg0 + F[1].y*wg1 + F[2].y*wg2 + F[3].y*wg3 + F[4].y*wg4; \
                acc[oh].z += F[0].z*wg0 + F[1].z*wg1 + F[2].z*wg2 + F[3].z*wg3 + F[4].z*wg4; \
                acc[oh].w += F[0].w*wg0 + F[1].w*wg1 + F[2].w*wg2 + F[3].w*wg3 + F[4].w*wg4; \
            }                                                                 \
        }                                                                     \
    }

    // 2-row-ahead software pipeline, statically-named triple buffers.
    LOADROW(fC, 2)  FMAROW(fA, 0)
    LOADROW(fA, 3)  FMAROW(fB, 1)
    LOADROW(fB, 4)  FMAROW(fC, 2)
    LOADROW(fC, 5)  FMAROW(fA, 3)
    LOADROW(fA, 6)  FMAROW(fB, 4)
    LOADROW(fB, 7)  FMAROW(fC, 5)
    LOADROW(fC, 8)  FMAROW(fA, 6)
    LOADROW(fA, 9)  FMAROW(fB, 7)
    LOADROW(fB, 10) FMAROW(fC, 8)
    LOADROW(fC, 11) FMAROW(fA, 9)
                    FMAROW(fB, 10)
                    FMAROW(fC, 11)

    // ---- Coalesced nontemporal stores: 8 rows x 1 KiB per wave. ----
    #pragma unroll
    for (int oh = 0; oh < VH; ++oh) {
        const size_t pix = (size_t)(b * HH + h0 + oh) * WW + (w0 + wL);
        vfloat4 v = { acc[oh].x, acc[oh].y, acc[oh].z, acc[oh].w };
        __builtin_nontemporal_store(v, (vfloat4*)(out + pix * CC + cg));
    }
}

extern "C" void kernel_launch(void* const* d_in, const int* in_sizes, int n_in,
                              void* d_out, int out_size, void* d_ws, size_t ws_size,
                              hipStream_t stream) {
    const float* feat = (const float*)d_in[0];
    const float* kern = (const float*)d_in[1];
    const float* bias = (const float*)d_in[2];
    float* out = (float*)d_out;

    dim3 grid(BB * (HH / VH) * (WW / TW));  // 1024 blocks
    dim3 block(TPB);
    kpn_conv_kernel<<<grid, block, 0, stream>>>(feat, kern, bias, out);
}